// Round 2
// baseline (284.715 us; speedup 1.0000x reference)
//
#include <hip/hip_runtime.h>
#include <math.h>

#define NB 32
#define NC 256
#define NH 64
#define NW 64
#define NHW (NH * NW)          // 4096
#define EPS_ 1e-5f

// ---------------------------------------------------------------------------
// K1: channel pooling. pooled[b][0][h][w] = max_c x, pooled[b][1][h][w] = mean_c x
// Block = 256 threads = 4 C-chunks x 64 hw-quads. Each wave (one C-chunk) does
// 64 consecutive float4 loads per channel -> 1 KiB coalesced transactions.
// ---------------------------------------------------------------------------
__global__ __launch_bounds__(256) void pool_k(const float* __restrict__ x,
                                              float* __restrict__ pooled) {
    const int tid = threadIdx.x;
    const int cchunk = tid >> 6;          // 0..3
    const int lane = tid & 63;            // hw-quad within block
    const int q = blockIdx.x * 64 + lane; // global hw-quad in [0, NB*NHW/4)
    const int b = q >> 10;                // NHW/4 = 1024
    const int hwq = q & 1023;

    const float4* __restrict__ xq = (const float4*)x;
    const int base = b * NC * (NHW / 4) + hwq;

    float4 mx = make_float4(-INFINITY, -INFINITY, -INFINITY, -INFINITY);
    float4 sm = make_float4(0.f, 0.f, 0.f, 0.f);
    const int c0 = cchunk * 64;
    #pragma unroll 4
    for (int c = c0; c < c0 + 64; ++c) {
        float4 v = xq[base + c * (NHW / 4)];
        mx.x = fmaxf(mx.x, v.x); mx.y = fmaxf(mx.y, v.y);
        mx.z = fmaxf(mx.z, v.z); mx.w = fmaxf(mx.w, v.w);
        sm.x += v.x; sm.y += v.y; sm.z += v.z; sm.w += v.w;
    }

    __shared__ float4 smax[4][64];
    __shared__ float4 ssum[4][64];
    smax[cchunk][lane] = mx;
    ssum[cchunk][lane] = sm;
    __syncthreads();

    if (cchunk == 0) {
        float4 m = smax[0][lane];
        float4 s = ssum[0][lane];
        #pragma unroll
        for (int k = 1; k < 4; ++k) {
            float4 m2 = smax[k][lane];
            float4 s2 = ssum[k][lane];
            m.x = fmaxf(m.x, m2.x); m.y = fmaxf(m.y, m2.y);
            m.z = fmaxf(m.z, m2.z); m.w = fmaxf(m.w, m2.w);
            s.x += s2.x; s.y += s2.y; s.z += s2.z; s.w += s2.w;
        }
        const float inv = 1.f / (float)NC;
        float4 mean = make_float4(s.x * inv, s.y * inv, s.z * inv, s.w * inv);
        float4* __restrict__ pq = (float4*)pooled;
        pq[(b * 2 + 0) * (NHW / 4) + hwq] = m;
        pq[(b * 2 + 1) * (NHW / 4) + hwq] = mean;
    }
}

// ---------------------------------------------------------------------------
// K2: att[b][h][w] = (sig(bn1(conv_w1)) + sig(bn2(conv_w2T)) + sig(bn3(conv_w3))) / 3
// Branch 2's transpose-conv-transpose == conv with w2's kernel spatially
// transposed (symmetric padding, H == W). One thread per output position.
// pooled (1 MiB) is L2-resident; weights broadcast from cache.
// ---------------------------------------------------------------------------
__global__ __launch_bounds__(256) void att_k(
    const float* __restrict__ pooled,
    const float* __restrict__ w1, const float* __restrict__ g1,
    const float* __restrict__ be1, const float* __restrict__ m1,
    const float* __restrict__ v1,
    const float* __restrict__ w2, const float* __restrict__ g2,
    const float* __restrict__ be2, const float* __restrict__ m2,
    const float* __restrict__ v2,
    const float* __restrict__ w3, const float* __restrict__ g3,
    const float* __restrict__ be3, const float* __restrict__ m3,
    const float* __restrict__ v3,
    float* __restrict__ att) {
    const int gid = blockIdx.x * 256 + threadIdx.x; // [0, NB*NHW)
    const int b = gid >> 12;                        // NHW = 4096
    const int hw = gid & (NHW - 1);
    const int h = hw >> 6;
    const int w = hw & 63;

    const float* __restrict__ pb = pooled + b * 2 * NHW;

    float s1 = 0.f, s2 = 0.f, s3 = 0.f;
    #pragma unroll
    for (int dh = -3; dh <= 3; ++dh) {
        const int y = h + dh;
        if ((unsigned)y >= (unsigned)NH) continue;
        #pragma unroll
        for (int dw = -3; dw <= 3; ++dw) {
            const int xx = w + dw;
            if ((unsigned)xx >= (unsigned)NW) continue;
            const int kh = dh + 3, kw = dw + 3;
            #pragma unroll
            for (int ci = 0; ci < 2; ++ci) {
                const float p = pb[ci * NHW + y * NW + xx];
                s1 = fmaf(p, w1[ci * 49 + kh * 7 + kw], s1);
                s2 = fmaf(p, w2[ci * 49 + kw * 7 + kh], s2); // transposed kernel
                s3 = fmaf(p, w3[ci * 49 + kh * 7 + kw], s3);
            }
        }
    }

    const float sc1 = g1[0] * rsqrtf(v1[0] + EPS_);
    const float sc2 = g2[0] * rsqrtf(v2[0] + EPS_);
    const float sc3 = g3[0] * rsqrtf(v3[0] + EPS_);
    const float y1 = (s1 - m1[0]) * sc1 + be1[0];
    const float y2 = (s2 - m2[0]) * sc2 + be2[0];
    const float y3 = (s3 - m3[0]) * sc3 + be3[0];

    const float a1 = 1.f / (1.f + expf(-y1));
    const float a2 = 1.f / (1.f + expf(-y2));
    const float a3 = 1.f / (1.f + expf(-y3));

    att[gid] = (a1 + a2 + a3) * (1.f / 3.f);
}

// ---------------------------------------------------------------------------
// K3: out[b][c][h][w] = x[b][c][h][w] * att[b][h][w]   (float4 grid-stride)
// ---------------------------------------------------------------------------
__global__ __launch_bounds__(256) void mul_k(const float* __restrict__ x,
                                             const float* __restrict__ att,
                                             float* __restrict__ out) {
    const float4* __restrict__ xq = (const float4*)x;
    const float4* __restrict__ aq = (const float4*)att;
    float4* __restrict__ oq = (float4*)out;
    const int total = NB * NC * NHW / 4; // 8388608
    for (int p = blockIdx.x * blockDim.x + threadIdx.x; p < total;
         p += gridDim.x * blockDim.x) {
        const int b = p >> 18;          // NC*NHW/4 = 262144 = 2^18
        const int hwq = p & 1023;       // hw-quad = p & (NHW/4 - 1)
        const float4 a = aq[b * (NHW / 4) + hwq];
        const float4 v = xq[p];
        oq[p] = make_float4(v.x * a.x, v.y * a.y, v.z * a.z, v.w * a.w);
    }
}

extern "C" void kernel_launch(void* const* d_in, const int* in_sizes, int n_in,
                              void* d_out, int out_size, void* d_ws, size_t ws_size,
                              hipStream_t stream) {
    const float* x  = (const float*)d_in[0];
    const float* w1 = (const float*)d_in[1];
    const float* g1 = (const float*)d_in[2];
    const float* b1 = (const float*)d_in[3];
    const float* m1 = (const float*)d_in[4];
    const float* v1 = (const float*)d_in[5];
    const float* w2 = (const float*)d_in[6];
    const float* g2 = (const float*)d_in[7];
    const float* b2 = (const float*)d_in[8];
    const float* m2 = (const float*)d_in[9];
    const float* v2 = (const float*)d_in[10];
    const float* w3 = (const float*)d_in[11];
    const float* g3 = (const float*)d_in[12];
    const float* b3 = (const float*)d_in[13];
    const float* m3 = (const float*)d_in[14];
    const float* v3 = (const float*)d_in[15];
    float* out = (float*)d_out;

    float* pooled = (float*)d_ws;                                   // NB*2*NHW floats = 1 MiB
    float* att = (float*)((char*)d_ws + (size_t)NB * 2 * NHW * 4);  // NB*NHW floats = 0.5 MiB

    // K1: 512 blocks x 256 thr (each block: 64 hw-quads x 4 C-chunks)
    pool_k<<<NB * NHW / 4 / 64, 256, 0, stream>>>(x, pooled);
    // K2: one thread per (b,h,w)
    att_k<<<NB * NHW / 256, 256, 0, stream>>>(pooled,
        w1, g1, b1, m1, v1, w2, g2, b2, m2, v2, w3, g3, b3, m3, v3, att);
    // K3: grid-stride float4 multiply
    mul_k<<<2048, 256, 0, stream>>>(x, att, out);
}